// Round 15
// baseline (117.290 us; speedup 1.0000x reference)
//
#include <hip/hip_runtime.h>
#include <hip/hip_bf16.h>
#include <stdint.h>

#define BB 2
#define TT 2048
#define CC 1024
#define HH 16
#define DD 64
#define MM (BB*TT)   // 4096 rows

typedef __bf16 bf16x8 __attribute__((ext_vector_type(8)));
typedef float  f32x4  __attribute__((ext_vector_type(4)));
typedef float  f32x16 __attribute__((ext_vector_type(16)));
typedef unsigned short u16;
typedef unsigned int   u32;

// float -> bf16 bits, RTNE
__device__ __forceinline__ u16 f2bf(float f) {
  u32 u = __float_as_uint(f);
  return (u16)((u + 0x7fffu + ((u >> 16) & 1u)) >> 16);
}

// packed f32x2 -> bf16x2 (single VALU op; RTNE) [T12]
__device__ __forceinline__ u32 cvt_pk_bf16(float a, float b) {
  u32 r;
  asm("v_cvt_pk_bf16_f32 %0, %1, %2" : "=v"(r) : "v"(a), "v"(b));
  return r;
}

// async global->LDS, 16B per lane. LDS dest is wave-uniform base (+lane*16 by HW).
__device__ __forceinline__ void gload_lds16(const u16* g, u16* l) {
  auto gp = (const u32 __attribute__((address_space(1)))*)(uintptr_t)g;
  auto lp = (u32 __attribute__((address_space(3)))*)(u32)(uintptr_t)l;
  __builtin_amdgcn_global_load_lds(gp, lp, 16, 0, 0);
}

// ---------------- kernel S: sentinel (ws too small -> diagnostic output) ------------
__global__ __launch_bounds__(256)
void k_sentinel(float* __restrict__ out, int n) {
  int i = blockIdx.x * 256 + threadIdx.x;
  if (i < n) out[i] = 9999.0f;
}

// ---------------- kernel 0: convert x fp32->bf16, weights int32->bf16 (exact) ------
__global__ __launch_bounds__(256)
void k_convert(const float* __restrict__ x,
               const int* __restrict__ w0, const int* __restrict__ w1,
               const int* __restrict__ w2, const int* __restrict__ w3,
               u16* __restrict__ xb, u16* __restrict__ wb) {
  const int idx = blockIdx.x * 256 + threadIdx.x;
  const int NX = MM * CC / 4;          // 1048576 float4 units
  if (idx < NX) {
    float4 v = ((const float4*)x)[idx];
    u32 lo = (u32)f2bf(v.x) | ((u32)f2bf(v.y) << 16);
    u32 hi = (u32)f2bf(v.z) | ((u32)f2bf(v.w) << 16);
    ((uint2*)xb)[idx] = make_uint2(lo, hi);
  } else {
    int u = idx - NX;                  // 0..1048575 ; 262144 4-weight units per matrix
    int mat = u >> 18;
    int j = u & 262143;
    const int* ws = (mat == 0) ? w0 : (mat == 1) ? w1 : (mat == 2) ? w2 : w3;
    int4 v = ((const int4*)ws)[j];     // weights presented as int32 (confirmed R2)
    u32 lo = (u32)f2bf((float)v.x) | ((u32)f2bf((float)v.y) << 16);
    u32 hi = (u32)f2bf((float)v.z) | ((u32)f2bf((float)v.w) << 16);
    ((uint2*)wb)[(mat << 18) + j] = make_uint2(lo, hi);
  }
}

// ---------------- shared GEMM core: C[128x128] = A[128xK] * W[128xK]^T --------------
// R13's verified structure (16KB LDS, two syncthreads/K-step): cross-block TLP at
// ~24% occupancy hides staging latency; R14's 32KB single-barrier variant dropped
// occupancy to 14.5% and regressed -- reverted.
__device__ __forceinline__ void gemm_core(const u16* __restrict__ Ag,
                                          const u16* __restrict__ Wg,
                                          int brow, int bcol,
                                          u16* As, u16* Bs, f32x4 acc[4][4]) {
  const int tid  = threadIdx.x;
  const int w    = tid >> 6;
  const int lane = tid & 63;
  const int q = lane & 15, g = lane >> 4;
  const int wm = w >> 1, wn = w & 1;

  for (int kt = 0; kt < CC / 32; ++kt) {
    #pragma unroll
    for (int i = 0; i < 2; ++i) {
      int Lg  = i * 256 + tid;         // granule id (16B each); [128][32]bf16 = 512 granules
      int row = Lg >> 2, gc = Lg & 3;
      gload_lds16(Ag + (brow + row) * CC + kt * 32 + gc * 8, As + (i * 256 + w * 64) * 8);
      gload_lds16(Wg + (bcol + row) * CC + kt * 32 + gc * 8, Bs + (i * 256 + w * 64) * 8);
    }
    __syncthreads();
    bf16x8 af[4], bff[4];
    #pragma unroll
    for (int a = 0; a < 4; ++a) af[a]  = *(const bf16x8*)&As[(wm * 64 + a * 16 + q) * 32 + g * 8];
    #pragma unroll
    for (int b = 0; b < 4; ++b) bff[b] = *(const bf16x8*)&Bs[(wn * 64 + b * 16 + q) * 32 + g * 8];
    #pragma unroll
    for (int a = 0; a < 4; ++a) {
      #pragma unroll
      for (int b = 0; b < 4; ++b) {
        acc[a][b] = __builtin_amdgcn_mfma_f32_16x16x32_bf16(af[a], bff[b], acc[a][b], 0, 0, 0);
      }
    }
    __syncthreads();
  }
}

// ---------------- kernel 1: QKV projection -> Q,K (B,H,T,D) and V^T (B,H,D,T) ------
// V blocks transpose through LDS (reusing the staging buffer): acc -> [64 d][136-pad]
// tile -> coalesced 64B stores along T (~256 lines/block vs 16K for direct d-major
// scatter). Epilogue verified correct in R14.
__global__ __launch_bounds__(256)
void k_gemm_qkv(const u16* __restrict__ xb, const u16* __restrict__ wb,
                const float* __restrict__ sq, const float* __restrict__ bq,
                const float* __restrict__ sk, const float* __restrict__ bk,
                const float* __restrict__ sv, const float* __restrict__ bv,
                u16* __restrict__ Qo, u16* __restrict__ Ko, u16* __restrict__ Vt) {
  __shared__ u16 sh[8704];             // 17.4KB: As=sh[0..4095], Bs=sh[4096..8191];
                                       // V-transpose tile [64][136] reuses all of it
  const int bid  = blockIdx.x;
  const int brow = (bid & 31) * 128;
  const int ncol = (bid >> 5) * 128;   // 0..3071
  const int mat  = ncol >> 10;
  const int bcol = ncol & 1023;
  const u16* W = wb + (mat << 20);

  f32x4 acc[4][4];
  #pragma unroll
  for (int a = 0; a < 4; ++a)
    #pragma unroll
    for (int b = 0; b < 4; ++b) { f32x4 z = {0.f, 0.f, 0.f, 0.f}; acc[a][b] = z; }

  gemm_core(xb, W, brow, bcol, sh, sh + 4096, acc);

  const int tid = threadIdx.x;
  const int w = tid >> 6, lane = tid & 63;
  const int q = lane & 15, g = lane >> 4;
  const int wm = w >> 1, wn = w & 1;
  const float* sarr = (mat == 0) ? sq : (mat == 1) ? sk : sv;
  const float* barr = (mat == 0) ? bq : (mat == 1) ? bk : bv;

  if (mat < 2) {
    // Q/K: direct scatter (4 lines per wave-store -- acceptable)
    u16* Out = (mat == 0) ? Qo : Ko;
    #pragma unroll
    for (int bt = 0; bt < 4; ++bt) {
      const int c = bcol + wn * 64 + bt * 16 + q;   // channel, 0..1023
      const float sc = sarr[c];
      const float bi = barr[c];
      const int h = c >> 6, d = c & 63;
      #pragma unroll
      for (int a = 0; a < 4; ++a) {
        #pragma unroll
        for (int r = 0; r < 4; ++r) {
          const int m = brow + wm * 64 + a * 16 + 4 * g + r;  // token row 0..4095
          const int b_ = m >> 11, t = m & 2047;
          Out[(((size_t)(b_ * HH + h) * TT) + t) * DD + d] = f2bf(acc[a][bt][r] * sc + bi);
        }
      }
    }
  } else {
    // V: LDS transpose -> coalesced V^T stores. Tile [64 d][136-pad m] per head.
    __syncthreads();                   // all waves done with gemm_core's LDS
    u16* lt = sh;                      // 64*136 = 8704 u16, exact fit
    const int b_ = brow >> 11, t0 = brow & 2047;
    #pragma unroll
    for (int hh = 0; hh < 2; ++hh) {
      if (wn == hh) {
        #pragma unroll
        for (int bt = 0; bt < 4; ++bt) {
          const int c = bcol + wn * 64 + bt * 16 + q;
          const float sc = sarr[c];
          const float bi = barr[c];
          #pragma unroll
          for (int a = 0; a < 4; ++a) {
            u32 lo  = cvt_pk_bf16(acc[a][bt][0] * sc + bi, acc[a][bt][1] * sc + bi);
            u32 hi2 = cvt_pk_bf16(acc[a][bt][2] * sc + bi, acc[a][bt][3] * sc + bi);
            *(uint2*)&lt[(bt * 16 + q) * 136 + wm * 64 + a * 16 + 4 * g] = make_uint2(lo, hi2);
          }
        }
      }
      __syncthreads();
      {
        const int d = tid >> 2, seg = tid & 3;
        const int hg = (bcol >> 6) + hh;          // global head index
        const size_t base = ((size_t)(b_ * HH + hg) * DD + d) * TT + t0 + seg * 32;
        #pragma unroll
        for (int j2 = 0; j2 < 4; ++j2)
          *(uint4*)&Vt[base + j2 * 8] = *(const uint4*)&lt[d * 136 + seg * 32 + j2 * 8];
      }
      __syncthreads();
    }
  }
}

// ---------------- kernel 2: causal flash attention, split-K, 1-barrier phases -------
// (verbatim R13 -- verified)
__global__ __launch_bounds__(256, 2)
void k_attn(const u16* __restrict__ Q, const u16* __restrict__ K,
            const u16* __restrict__ Vt, u16* __restrict__ Y) {
  __shared__ u16 kbuf[2][2][64 * 64];  // [dbuf][kb-parity][key][d], row-swizzled
  __shared__ u16 vbuf[2][2][64 * 64];  // [dbuf][kb-parity][d][key], row-swizzled
  const int tid = threadIdx.x;
  const int w = tid >> 6, lane = tid & 63;
  const int q = lane & 31, hi = lane >> 5;
  const int r = w >> 1, u_ = w & 1;              // row-half, key-parity
  const int bid = blockIdx.x;
  const int bh = bid & 31;                       // head-batch -> XCD = bh%8 (L2 pin)
  const int j  = (bid >> 5) & 7;
  const int qt = bid >> 8;                       // dispatch quarter (0 first = largest)
  const int v  = (qt == 0) ? (31 - j) : (qt == 1) ? (16 + j)
               : (qt == 2) ? (15 - j) : j;       // quartet work sums to 66 kb exactly
  const int qw = v * 64 + 32 * r;                // this wave's 32 q-rows
  const int qg = qw + q;                         // this lane's q-row
  const u16* Qh = Q  + (size_t)bh * TT * DD;
  const u16* Kh = K  + (size_t)bh * TT * DD;
  const u16* Vh = Vt + (size_t)bh * DD * TT;
  const int b_ = bh >> 4, h = bh & 15;
  constexpr float SE = 0.125f * 1.44269504088896340736f;  // scale * log2(e)

  // Q fragments: B-operand, col=q, k(=d) = 16c + 8hi + e
  bf16x8 qf[4];
  #pragma unroll
  for (int c = 0; c < 4; ++c)
    qf[c] = *(const bf16x8*)&Qh[(qw + q) * DD + 16 * c + 8 * hi];

  f32x16 oacc[2];                                // O^T[32d x 32q] per d-tile
  oacc[0] = f32x16{}; oacc[1] = f32x16{};
  float m_run = -1.0e30f;                        // finite: keeps exp2 args NaN-free
  float l_vec[8];
  #pragma unroll
  for (int u2 = 0; u2 < 8; ++u2) l_vec[u2] = 0.f;

  const int nkb = v + 1;                         // 64-key blocks for this tile
  const int P = (nkb + 1) >> 1;                  // phases (2 kb per phase)

  #define STAGE(BUFI, PH)                                                           \
    {                                                                               \
      int kbA = min(128 * (PH), TT - 64);                                           \
      int kbB = min(128 * (PH) + 64, TT - 64);                                      \
      _Pragma("unroll")                                                             \
      for (int jj = 0; jj < 2; ++jj) {                                              \
        int kbase_j = jj ? kbB : kbA;                                               \
        _Pragma("unroll")                                                           \
        for (int r2 = 0; r2 < 2; ++r2) {                                            \
          int g = r2 * 256 + tid;                                                   \
          int row = g >> 3, cB = (g & 7) << 4;                                      \
          int scB = cB ^ ((row & 7) << 4);                                          \
          gload_lds16(Kh + (size_t)(kbase_j + row) * DD + (scB >> 1),               \
                      &kbuf[BUFI][jj][(r2 * 256 + w * 64) * 8]);                    \
        }                                                                           \
        _Pragma("unroll")                                                           \
        for (int r2 = 0; r2 < 2; ++r2) {                                            \
          int g = r2 * 256 + tid;                                                   \
          int row = g >> 3, cB = (g & 7) << 4;                                      \
          int scB = cB ^ ((row & 7) << 4);                                          \
          gload_lds16(Vh + (size_t)row * TT + kbase_j + (scB >> 1),                 \
                      &vbuf[BUFI][jj][(r2 * 256 + w * 64) * 8]);                    \
        }                                                                           \
      }                                                                             \
    }

  STAGE(0, 0);
  for (int i = 0; i < P; ++i) {
    // own STAGE(i) loads are the ONLY outstanding VMEM here -> vmcnt(0) is exact
    asm volatile("s_waitcnt vmcnt(0)" ::: "memory");
    __builtin_amdgcn_s_barrier();                        // publish staging; fence dbuf
    __builtin_amdgcn_sched_barrier(0);                   // rule 18: pin ds_reads after
    if (i + 1 < P) STAGE((i + 1) & 1, i + 1);            // hides under compute(i)

    const int kb2 = 2 * i + u_;                          // this wave's key-block
    if (kb2 < nkb) {                                     // wave-uniform
      const int kbase = kb2 * 64;
      const u16* kl = kbuf[i & 1][u_];
      const u16* vl = vbuf[i & 1][u_];

      // K fragments: A-operand, row=key(lane&31)+32s, k(=d) = 16c + 8hi + e
      bf16x8 kf[2][4];
      #pragma unroll
      for (int s = 0; s < 2; ++s)
        #pragma unroll
        for (int c = 0; c < 4; ++c) {
          const int row = 32 * s + q, cB = 32 * c + 16 * hi;
          kf[s][c] = *(const bf16x8*)&kl[(row * 128 + (cB ^ ((row & 7) << 4))) >> 1];
        }
      f32x16 sacc[2];
      sacc[0] = f32x16{}; sacc[1] = f32x16{};
      __builtin_amdgcn_s_setprio(1);
      #pragma unroll
      for (int c = 0; c < 4; ++c) {
        sacc[0] = __builtin_amdgcn_mfma_f32_32x32x16_bf16(kf[0][c], qf[c], sacc[0], 0, 0, 0);
        sacc[1] = __builtin_amdgcn_mfma_f32_32x32x16_bf16(kf[1][c], qf[c], sacc[1], 0, 0, 0);
      }
      __builtin_amdgcn_s_setprio(0);

      // V fragments: A-operand, row=d_local, k(=key) = 8hi + e within slice (s,c2)
      bf16x8 vf[2][2][2];
      #pragma unroll
      for (int dt = 0; dt < 2; ++dt)
        #pragma unroll
        for (int s = 0; s < 2; ++s)
          #pragma unroll
          for (int c2 = 0; c2 < 2; ++c2) {
            const int row = dt * 32 + q, cB = 64 * s + 32 * c2 + 16 * hi;
            vf[dt][s][c2] = *(const bf16x8*)&vl[(row * 128 + (cB ^ ((row & 7) << 4))) >> 1];
          }

      // ---- softmax over this lane's 32 scores (key = 32s + (r&3)+8(r>>2)+4hi) ----
      float sr[32];
      #pragma unroll
      for (int s = 0; s < 2; ++s)
        #pragma unroll
        for (int rr = 0; rr < 16; ++rr) sr[s * 16 + rr] = sacc[s][rr];
      if (kbase + 63 > qw) {                     // causal-partial block for this wave
        #pragma unroll
        for (int s = 0; s < 2; ++s)
          #pragma unroll
          for (int rr = 0; rr < 16; ++rr)
            if (kbase + 32 * s + (rr & 3) + 8 * (rr >> 2) + 4 * hi > qg)
              sr[s * 16 + rr] = -__builtin_inff();
      }
      float mx[16];
      #pragma unroll
      for (int u2 = 0; u2 < 16; ++u2) mx[u2] = fmaxf(sr[u2], sr[u2 + 16]);
      #pragma unroll
      for (int st = 8; st > 0; st >>= 1)
        #pragma unroll
        for (int u2 = 0; u2 < st; ++u2) mx[u2] = fmaxf(mx[u2], mx[u2 + st]);
      const float pmax = fmaxf(mx[0], __shfl_xor(mx[0], 32)) * SE;   // finite always
      const bool keep = __all(pmax <= m_run + 8.0f);   // defer-max THR=8
      const float m_new = keep ? m_run : fmaxf(m_run, pmax);
      const float nm = -m_new;
      float p[32];
      #pragma unroll
      for (int u2 = 0; u2 < 32; ++u2)
        p[u2] = __builtin_amdgcn_exp2f(fmaf(sr[u2], SE, nm));
      if (!keep) {
        const float alpha = __builtin_amdgcn_exp2f(m_run - m_new);
        m_run = m_new;
        oacc[0] *= alpha;
        oacc[1] *= alpha;
        #pragma unroll
        for (int u2 = 0; u2 < 8; ++u2) l_vec[u2] *= alpha;
      }
      float t16[16];
      #pragma unroll
      for (int u2 = 0; u2 < 16; ++u2) t16[u2] = p[u2] + p[u2 + 16];
      #pragma unroll
      for (int u2 = 0; u2 < 8; ++u2) l_vec[u2] += t16[u2] + t16[u2 + 8];

      // ---- in-register P redistribution (T12), R9-verified pairing ----
      u32 Aw[8], Bw[8];
      #pragma unroll
      for (int n = 0; n < 8; ++n) {
        const int base = ((n >> 2) * 16) + ((n & 3) << 2);
        Aw[n] = cvt_pk_bf16(p[base + 0], p[base + 1]);
        Bw[n] = cvt_pk_bf16(p[base + 2], p[base + 3]);
      }
      bf16x8 pf[2][2];
      #pragma unroll
      for (int s = 0; s < 2; ++s)
        #pragma unroll
        for (int c2 = 0; c2 < 2; ++c2) {
          const int n0 = 4 * s + 2 * c2;
          u32 x0 = Aw[n0], x2 = Aw[n0 + 1];
          asm volatile("v_permlane32_swap_b32 %0, %1" : "+v"(x0), "+v"(x2));
          u32 x1 = Bw[n0], x3 = Bw[n0 + 1];
          asm volatile("v_permlane32_swap_b32 %0, %1" : "+v"(x1), "+v"(x3));
          union { u32 uw[4]; bf16x8 vv; } U;
          U.uw[0] = x0; U.uw[1] = x1; U.uw[2] = x2; U.uw[3] = x3;
          pf[s][c2] = U.vv;
        }

      // ---- PV: O^T[64d][32q] += V^T * P^T ----
      __builtin_amdgcn_s_setprio(1);
      #pragma unroll
      for (int s = 0; s < 2; ++s)
        #pragma unroll
        for (int c2 = 0; c2 < 2; ++c2) {
          oacc[0] = __builtin_amdgcn_mfma_f32_32x32x16_bf16(vf[0][s][c2], pf[s][c2], oacc[0], 0, 0, 0);
          oacc[1] = __builtin_amdgcn_mfma_f32_32x32x16_bf16(vf[1][s][c2], pf[s][c2], oacc[1], 0, 0, 0);
        }
      __builtin_amdgcn_s_setprio(0);
    }
  }
  #undef STAGE

  // ---- split-K merge over u (R9-proven), scratch = kbuf reuse ----
  __syncthreads();                               // all waves done reading kbuf/vbuf
  float l_run = ((l_vec[0] + l_vec[1]) + (l_vec[2] + l_vec[3]))
              + ((l_vec[4] + l_vec[5]) + (l_vec[6] + l_vec[7]));
  float* ms = ((float*)kbuf) + (r * 64 + lane) * 37;   // 2 pairs x 64 lanes x 37 f32
  if (u_ == 1) {
    #pragma unroll
    for (int dt = 0; dt < 2; ++dt)
      #pragma unroll
      for (int e = 0; e < 16; ++e) ms[dt * 16 + e] = oacc[dt][e];
    ms[32] = m_run;
    ms[33] = l_run;
  }
  __syncthreads();
  if (u_ == 0) {
    const float m1 = ms[32], l1 = ms[33];
    const float mt = fmaxf(m_run, m1);
    const float s0 = __builtin_amdgcn_exp2f(m_run - mt);
    const float s1 = __builtin_amdgcn_exp2f(m1 - mt);    // m1=-1e30 (idle wave) -> 0
    float lt = l_run * s0 + l1 * s1;
    lt += __shfl_xor(lt, 32);                            // cross-half partial l
    const float inv = 1.f / (lt + 1e-8f);
    #pragma unroll
    for (int dt = 0; dt < 2; ++dt)
      #pragma unroll
      for (int n = 0; n < 4; ++n) {
        const float o0 = (oacc[dt][4 * n + 0] * s0 + ms[dt * 16 + 4 * n + 0] * s1) * inv;
        const float o1 = (oacc[dt][4 * n + 1] * s0 + ms[dt * 16 + 4 * n + 1] * s1) * inv;
        const float o2 = (oacc[dt][4 * n + 2] * s0 + ms[dt * 16 + 4 * n + 2] * s1) * inv;
        const float o3 = (oacc[dt][4 * n + 3] * s0 + ms[dt * 16 + 4 * n + 3] * s1) * inv;
        u32 lo  = cvt_pk_bf16(o0, o1);
        u32 hi2 = cvt_pk_bf16(o2, o3);
        // d = 32dt + 8n + 4hi + {0..3}
        *(uint2*)&Y[(size_t)(b_ * TT + qg) * CC + h * 64 + 32 * dt + 8 * n + 4 * hi]
          = make_uint2(lo, hi2);
      }
  }
}

// ---------------- kernel 3: output projection -> fp32 d_out -------------------------
__global__ __launch_bounds__(256)
void k_gemm_o(const u16* __restrict__ Yb, const u16* __restrict__ Wo,
              const float* __restrict__ so, const float* __restrict__ bo,
              float* __restrict__ out) {
  __shared__ u16 As[128 * 32];
  __shared__ u16 Bs[128 * 32];
  const int bid = blockIdx.x;
  const int brow = (bid & 31) * 128;
  const int bcol = (bid >> 5) * 128;
  f32x4 acc[4][4];
  #pragma unroll
  for (int a = 0; a < 4; ++a)
    #pragma unroll
    for (int b = 0; b < 4; ++b) { f32x4 z = {0.f, 0.f, 0.f, 0.f}; acc[a][b] = z; }

  gemm_core(Yb, Wo, brow, bcol, As, Bs, acc);

  const int tid = threadIdx.x;
  const int w = tid >> 6, lane = tid & 63;
  const int q = lane & 15, g = lane >> 4;
  const int wm = w >> 1, wn = w & 1;
  #pragma unroll
  for (int bt = 0; bt < 4; ++bt) {
    const int c = bcol + wn * 64 + bt * 16 + q;
    const float sc = so[c], bi = bo[c];
    #pragma unroll
    for (int a = 0; a < 4; ++a) {
      const int mbase = brow + wm * 64 + a * 16 + 4 * g;
      #pragma unroll
      for (int r = 0; r < 4; ++r) {
        out[(size_t)(mbase + r) * CC + c] = acc[a][bt][r] * sc + bi;
      }
    }
  }
}

// ---------------- launcher -----------------------------------------------------------
extern "C" void kernel_launch(void* const* d_in, const int* in_sizes, int n_in,
                              void* d_out, int out_size, void* d_ws, size_t ws_size,
                              hipStream_t stream) {
  const float* x  = (const float*)d_in[0];
  const int*   wq = (const int*)d_in[1];
  const float* sq = (const float*)d_in[2];
  const float* bq = (const float*)d_in[3];
  const int*   wk = (const int*)d_in[4];
  const float* sk = (const float*)d_in[5];
  const float* bk = (const float*)d_in[6];
  const int*   wv = (const int*)d_in[7];
  const float* sv = (const float*)d_in[8];
  const float* bv = (const float*)d_in[9];
  const int*   wo = (const int*)d_in[10];
  const float* so = (const float*)d_in[11];
  const float* bo = (const float*)d_in[12];

  const size_t NEED = (40u << 20);
  if (ws_size < NEED) {   // diagnostic: error magnitude ~9999 => scratch too small
    k_sentinel<<<dim3((out_size + 255) / 256), dim3(256), 0, stream>>>((float*)d_out, out_size);
    return;
  }

  char* ws = (char*)d_ws;
  u16* xb = (u16*)(ws);                      // 8 MB  (x bf16; reused as Y later)
  u16* wb = (u16*)(ws + (8u  << 20));        // 8 MB  (4 weight matrices bf16)
  u16* Qb = (u16*)(ws + (16u << 20));        // 8 MB
  u16* Kb = (u16*)(ws + (24u << 20));        // 8 MB
  u16* Vt = (u16*)(ws + (32u << 20));        // 8 MB  (V^T, written directly by QKV GEMM)
  u16* Yb = xb;                              // x dead after QKV GEMM

  k_convert <<<dim3(8192), dim3(256), 0, stream>>>(x, wq, wk, wv, wo, xb, wb);
  k_gemm_qkv<<<dim3(768),  dim3(256), 0, stream>>>(xb, wb, sq, bq, sk, bk, sv, bv, Qb, Kb, Vt);
  k_attn    <<<dim3(1024), dim3(256), 0, stream>>>(Qb, Kb, Vt, Yb);
  k_gemm_o  <<<dim3(256),  dim3(256), 0, stream>>>(Yb, wb + (3u << 20), so, bo, (float*)d_out);
}

// Round 16
// 105.007 us; speedup vs baseline: 1.1170x; 1.1170x over previous
//
#include <hip/hip_runtime.h>
#include <hip/hip_bf16.h>
#include <stdint.h>

#define BB 2
#define TT 2048
#define CC 1024
#define HH 16
#define DD 64
#define MM (BB*TT)   // 4096 rows

typedef __bf16 bf16x8 __attribute__((ext_vector_type(8)));
typedef float  f32x4  __attribute__((ext_vector_type(4)));
typedef float  f32x16 __attribute__((ext_vector_type(16)));
typedef unsigned short u16;
typedef unsigned int   u32;

// float -> bf16 bits, RTNE
__device__ __forceinline__ u16 f2bf(float f) {
  u32 u = __float_as_uint(f);
  return (u16)((u + 0x7fffu + ((u >> 16) & 1u)) >> 16);
}

// packed f32x2 -> bf16x2 (single VALU op; RTNE) [T12]
__device__ __forceinline__ u32 cvt_pk_bf16(float a, float b) {
  u32 r;
  asm("v_cvt_pk_bf16_f32 %0, %1, %2" : "=v"(r) : "v"(a), "v"(b));
  return r;
}

// async global->LDS, 16B per lane. LDS dest is wave-uniform base (+lane*16 by HW).
__device__ __forceinline__ void gload_lds16(const u16* g, u16* l) {
  auto gp = (const u32 __attribute__((address_space(1)))*)(uintptr_t)g;
  auto lp = (u32 __attribute__((address_space(3)))*)(u32)(uintptr_t)l;
  __builtin_amdgcn_global_load_lds(gp, lp, 16, 0, 0);
}

// ---------------- kernel S: sentinel (ws too small -> diagnostic output) ------------
__global__ __launch_bounds__(256)
void k_sentinel(float* __restrict__ out, int n) {
  int i = blockIdx.x * 256 + threadIdx.x;
  if (i < n) out[i] = 9999.0f;
}

// ---------------- kernel 0: convert x fp32->bf16, weights int32->bf16 (exact) ------
__global__ __launch_bounds__(256)
void k_convert(const float* __restrict__ x,
               const int* __restrict__ w0, const int* __restrict__ w1,
               const int* __restrict__ w2, const int* __restrict__ w3,
               u16* __restrict__ xb, u16* __restrict__ wb) {
  const int idx = blockIdx.x * 256 + threadIdx.x;
  const int NX = MM * CC / 4;          // 1048576 float4 units
  if (idx < NX) {
    float4 v = ((const float4*)x)[idx];
    u32 lo = (u32)f2bf(v.x) | ((u32)f2bf(v.y) << 16);
    u32 hi = (u32)f2bf(v.z) | ((u32)f2bf(v.w) << 16);
    ((uint2*)xb)[idx] = make_uint2(lo, hi);
  } else {
    int u = idx - NX;                  // 0..1048575 ; 262144 4-weight units per matrix
    int mat = u >> 18;
    int j = u & 262143;
    const int* ws = (mat == 0) ? w0 : (mat == 1) ? w1 : (mat == 2) ? w2 : w3;
    int4 v = ((const int4*)ws)[j];     // weights presented as int32 (confirmed R2)
    u32 lo = (u32)f2bf((float)v.x) | ((u32)f2bf((float)v.y) << 16);
    u32 hi = (u32)f2bf((float)v.z) | ((u32)f2bf((float)v.w) << 16);
    ((uint2*)wb)[(mat << 18) + j] = make_uint2(lo, hi);
  }
}

// ---------------- shared GEMM core: C[128x128] = A[128xK] * W[128xK]^T --------------
// R13's verified structure (16KB LDS, two syncthreads/K-step): cross-block TLP at
// ~24% occupancy hides staging latency (R14/R15 proved occupancy is the mechanism).
__device__ __forceinline__ void gemm_core(const u16* __restrict__ Ag,
                                          const u16* __restrict__ Wg,
                                          int brow, int bcol,
                                          u16* As, u16* Bs, f32x4 acc[4][4]) {
  const int tid  = threadIdx.x;
  const int w    = tid >> 6;
  const int lane = tid & 63;
  const int q = lane & 15, g = lane >> 4;
  const int wm = w >> 1, wn = w & 1;

  for (int kt = 0; kt < CC / 32; ++kt) {
    #pragma unroll
    for (int i = 0; i < 2; ++i) {
      int Lg  = i * 256 + tid;         // granule id (16B each); [128][32]bf16 = 512 granules
      int row = Lg >> 2, gc = Lg & 3;
      gload_lds16(Ag + (brow + row) * CC + kt * 32 + gc * 8, As + (i * 256 + w * 64) * 8);
      gload_lds16(Wg + (bcol + row) * CC + kt * 32 + gc * 8, Bs + (i * 256 + w * 64) * 8);
    }
    __syncthreads();
    bf16x8 af[4], bff[4];
    #pragma unroll
    for (int a = 0; a < 4; ++a) af[a]  = *(const bf16x8*)&As[(wm * 64 + a * 16 + q) * 32 + g * 8];
    #pragma unroll
    for (int b = 0; b < 4; ++b) bff[b] = *(const bf16x8*)&Bs[(wn * 64 + b * 16 + q) * 32 + g * 8];
    #pragma unroll
    for (int a = 0; a < 4; ++a) {
      #pragma unroll
      for (int b = 0; b < 4; ++b) {
        acc[a][b] = __builtin_amdgcn_mfma_f32_16x16x32_bf16(af[a], bff[b], acc[a][b], 0, 0, 0);
      }
    }
    __syncthreads();
  }
}

// ---------------- kernel 1: QKV projection -> Q,K (B,H,T,D) and V^T (B,H,D,T) ------
// Exact R13 (verified best): direct scatter epilogue for Q, K, and V^T. R15 proved
// the LDS-transpose V epilogue costs more in occupancy (VGPR 76->96) than it saves
// in store coalescing.
__global__ __launch_bounds__(256)
void k_gemm_qkv(const u16* __restrict__ xb, const u16* __restrict__ wb,
                const float* __restrict__ sq, const float* __restrict__ bq,
                const float* __restrict__ sk, const float* __restrict__ bk,
                const float* __restrict__ sv, const float* __restrict__ bv,
                u16* __restrict__ Qo, u16* __restrict__ Ko, u16* __restrict__ Vt) {
  __shared__ u16 As[128 * 32];
  __shared__ u16 Bs[128 * 32];
  const int bid  = blockIdx.x;
  const int brow = (bid & 31) * 128;
  const int ncol = (bid >> 5) * 128;   // 0..3071
  const int mat  = ncol >> 10;
  const int bcol = ncol & 1023;
  const u16* W = wb + (mat << 20);

  f32x4 acc[4][4];
  #pragma unroll
  for (int a = 0; a < 4; ++a)
    #pragma unroll
    for (int b = 0; b < 4; ++b) { f32x4 z = {0.f, 0.f, 0.f, 0.f}; acc[a][b] = z; }

  gemm_core(xb, W, brow, bcol, As, Bs, acc);

  const int tid = threadIdx.x;
  const int w = tid >> 6, lane = tid & 63;
  const int q = lane & 15, g = lane >> 4;
  const int wm = w >> 1, wn = w & 1;
  const float* sarr = (mat == 0) ? sq : (mat == 1) ? sk : sv;
  const float* barr = (mat == 0) ? bq : (mat == 1) ? bk : bv;

  #pragma unroll
  for (int bt = 0; bt < 4; ++bt) {
    const int c = bcol + wn * 64 + bt * 16 + q;   // channel within matrix, 0..1023
    const float sc = sarr[c];
    const float bi = barr[c];
    const int h = c >> 6, d = c & 63;
    #pragma unroll
    for (int a = 0; a < 4; ++a) {
      #pragma unroll
      for (int r = 0; r < 4; ++r) {
        const int m = brow + wm * 64 + a * 16 + 4 * g + r;  // token row 0..4095
        const int b_ = m >> 11, t = m & 2047;
        const u16 val = f2bf(acc[a][bt][r] * sc + bi);
        if (mat == 0)      Qo[(((size_t)(b_ * HH + h) * TT) + t) * DD + d] = val;
        else if (mat == 1) Ko[(((size_t)(b_ * HH + h) * TT) + t) * DD + d] = val;
        else               Vt[((size_t)(b_ * HH + h) * DD + d) * TT + t] = val;  // V^T direct
      }
    }
  }
}

// ---------------- kernel 2: causal flash attention, split-K, 1-barrier phases -------
// (verbatim R13 -- verified)
__global__ __launch_bounds__(256, 2)
void k_attn(const u16* __restrict__ Q, const u16* __restrict__ K,
            const u16* __restrict__ Vt, u16* __restrict__ Y) {
  __shared__ u16 kbuf[2][2][64 * 64];  // [dbuf][kb-parity][key][d], row-swizzled
  __shared__ u16 vbuf[2][2][64 * 64];  // [dbuf][kb-parity][d][key], row-swizzled
  const int tid = threadIdx.x;
  const int w = tid >> 6, lane = tid & 63;
  const int q = lane & 31, hi = lane >> 5;
  const int r = w >> 1, u_ = w & 1;              // row-half, key-parity
  const int bid = blockIdx.x;
  const int bh = bid & 31;                       // head-batch -> XCD = bh%8 (L2 pin)
  const int j  = (bid >> 5) & 7;
  const int qt = bid >> 8;                       // dispatch quarter (0 first = largest)
  const int v  = (qt == 0) ? (31 - j) : (qt == 1) ? (16 + j)
               : (qt == 2) ? (15 - j) : j;       // quartet work sums to 66 kb exactly
  const int qw = v * 64 + 32 * r;                // this wave's 32 q-rows
  const int qg = qw + q;                         // this lane's q-row
  const u16* Qh = Q  + (size_t)bh * TT * DD;
  const u16* Kh = K  + (size_t)bh * TT * DD;
  const u16* Vh = Vt + (size_t)bh * DD * TT;
  const int b_ = bh >> 4, h = bh & 15;
  constexpr float SE = 0.125f * 1.44269504088896340736f;  // scale * log2(e)

  // Q fragments: B-operand, col=q, k(=d) = 16c + 8hi + e
  bf16x8 qf[4];
  #pragma unroll
  for (int c = 0; c < 4; ++c)
    qf[c] = *(const bf16x8*)&Qh[(qw + q) * DD + 16 * c + 8 * hi];

  f32x16 oacc[2];                                // O^T[32d x 32q] per d-tile
  oacc[0] = f32x16{}; oacc[1] = f32x16{};
  float m_run = -1.0e30f;                        // finite: keeps exp2 args NaN-free
  float l_vec[8];
  #pragma unroll
  for (int u2 = 0; u2 < 8; ++u2) l_vec[u2] = 0.f;

  const int nkb = v + 1;                         // 64-key blocks for this tile
  const int P = (nkb + 1) >> 1;                  // phases (2 kb per phase)

  #define STAGE(BUFI, PH)                                                           \
    {                                                                               \
      int kbA = min(128 * (PH), TT - 64);                                           \
      int kbB = min(128 * (PH) + 64, TT - 64);                                      \
      _Pragma("unroll")                                                             \
      for (int jj = 0; jj < 2; ++jj) {                                              \
        int kbase_j = jj ? kbB : kbA;                                               \
        _Pragma("unroll")                                                           \
        for (int r2 = 0; r2 < 2; ++r2) {                                            \
          int g = r2 * 256 + tid;                                                   \
          int row = g >> 3, cB = (g & 7) << 4;                                      \
          int scB = cB ^ ((row & 7) << 4);                                          \
          gload_lds16(Kh + (size_t)(kbase_j + row) * DD + (scB >> 1),               \
                      &kbuf[BUFI][jj][(r2 * 256 + w * 64) * 8]);                    \
        }                                                                           \
        _Pragma("unroll")                                                           \
        for (int r2 = 0; r2 < 2; ++r2) {                                            \
          int g = r2 * 256 + tid;                                                   \
          int row = g >> 3, cB = (g & 7) << 4;                                      \
          int scB = cB ^ ((row & 7) << 4);                                          \
          gload_lds16(Vh + (size_t)row * TT + kbase_j + (scB >> 1),                 \
                      &vbuf[BUFI][jj][(r2 * 256 + w * 64) * 8]);                    \
        }                                                                           \
      }                                                                             \
    }

  STAGE(0, 0);
  for (int i = 0; i < P; ++i) {
    // own STAGE(i) loads are the ONLY outstanding VMEM here -> vmcnt(0) is exact
    asm volatile("s_waitcnt vmcnt(0)" ::: "memory");
    __builtin_amdgcn_s_barrier();                        // publish staging; fence dbuf
    __builtin_amdgcn_sched_barrier(0);                   // rule 18: pin ds_reads after
    if (i + 1 < P) STAGE((i + 1) & 1, i + 1);            // hides under compute(i)

    const int kb2 = 2 * i + u_;                          // this wave's key-block
    if (kb2 < nkb) {                                     // wave-uniform
      const int kbase = kb2 * 64;
      const u16* kl = kbuf[i & 1][u_];
      const u16* vl = vbuf[i & 1][u_];

      // K fragments: A-operand, row=key(lane&31)+32s, k(=d) = 16c + 8hi + e
      bf16x8 kf[2][4];
      #pragma unroll
      for (int s = 0; s < 2; ++s)
        #pragma unroll
        for (int c = 0; c < 4; ++c) {
          const int row = 32 * s + q, cB = 32 * c + 16 * hi;
          kf[s][c] = *(const bf16x8*)&kl[(row * 128 + (cB ^ ((row & 7) << 4))) >> 1];
        }
      f32x16 sacc[2];
      sacc[0] = f32x16{}; sacc[1] = f32x16{};
      __builtin_amdgcn_s_setprio(1);
      #pragma unroll
      for (int c = 0; c < 4; ++c) {
        sacc[0] = __builtin_amdgcn_mfma_f32_32x32x16_bf16(kf[0][c], qf[c], sacc[0], 0, 0, 0);
        sacc[1] = __builtin_amdgcn_mfma_f32_32x32x16_bf16(kf[1][c], qf[c], sacc[1], 0, 0, 0);
      }
      __builtin_amdgcn_s_setprio(0);

      // V fragments: A-operand, row=d_local, k(=key) = 8hi + e within slice (s,c2)
      bf16x8 vf[2][2][2];
      #pragma unroll
      for (int dt = 0; dt < 2; ++dt)
        #pragma unroll
        for (int s = 0; s < 2; ++s)
          #pragma unroll
          for (int c2 = 0; c2 < 2; ++c2) {
            const int row = dt * 32 + q, cB = 64 * s + 32 * c2 + 16 * hi;
            vf[dt][s][c2] = *(const bf16x8*)&vl[(row * 128 + (cB ^ ((row & 7) << 4))) >> 1];
          }

      // ---- softmax over this lane's 32 scores (key = 32s + (r&3)+8(r>>2)+4hi) ----
      float sr[32];
      #pragma unroll
      for (int s = 0; s < 2; ++s)
        #pragma unroll
        for (int rr = 0; rr < 16; ++rr) sr[s * 16 + rr] = sacc[s][rr];
      if (kbase + 63 > qw) {                     // causal-partial block for this wave
        #pragma unroll
        for (int s = 0; s < 2; ++s)
          #pragma unroll
          for (int rr = 0; rr < 16; ++rr)
            if (kbase + 32 * s + (rr & 3) + 8 * (rr >> 2) + 4 * hi > qg)
              sr[s * 16 + rr] = -__builtin_inff();
      }
      float mx[16];
      #pragma unroll
      for (int u2 = 0; u2 < 16; ++u2) mx[u2] = fmaxf(sr[u2], sr[u2 + 16]);
      #pragma unroll
      for (int st = 8; st > 0; st >>= 1)
        #pragma unroll
        for (int u2 = 0; u2 < st; ++u2) mx[u2] = fmaxf(mx[u2], mx[u2 + st]);
      const float pmax = fmaxf(mx[0], __shfl_xor(mx[0], 32)) * SE;   // finite always
      const bool keep = __all(pmax <= m_run + 8.0f);   // defer-max THR=8
      const float m_new = keep ? m_run : fmaxf(m_run, pmax);
      const float nm = -m_new;
      float p[32];
      #pragma unroll
      for (int u2 = 0; u2 < 32; ++u2)
        p[u2] = __builtin_amdgcn_exp2f(fmaf(sr[u2], SE, nm));
      if (!keep) {
        const float alpha = __builtin_amdgcn_exp2f(m_run - m_new);
        m_run = m_new;
        oacc[0] *= alpha;
        oacc[1] *= alpha;
        #pragma unroll
        for (int u2 = 0; u2 < 8; ++u2) l_vec[u2] *= alpha;
      }
      float t16[16];
      #pragma unroll
      for (int u2 = 0; u2 < 16; ++u2) t16[u2] = p[u2] + p[u2 + 16];
      #pragma unroll
      for (int u2 = 0; u2 < 8; ++u2) l_vec[u2] += t16[u2] + t16[u2 + 8];

      // ---- in-register P redistribution (T12), R9-verified pairing ----
      u32 Aw[8], Bw[8];
      #pragma unroll
      for (int n = 0; n < 8; ++n) {
        const int base = ((n >> 2) * 16) + ((n & 3) << 2);
        Aw[n] = cvt_pk_bf16(p[base + 0], p[base + 1]);
        Bw[n] = cvt_pk_bf16(p[base + 2], p[base + 3]);
      }
      bf16x8 pf[2][2];
      #pragma unroll
      for (int s = 0; s < 2; ++s)
        #pragma unroll
        for (int c2 = 0; c2 < 2; ++c2) {
          const int n0 = 4 * s + 2 * c2;
          u32 x0 = Aw[n0], x2 = Aw[n0 + 1];
          asm volatile("v_permlane32_swap_b32 %0, %1" : "+v"(x0), "+v"(x2));
          u32 x1 = Bw[n0], x3 = Bw[n0 + 1];
          asm volatile("v_permlane32_swap_b32 %0, %1" : "+v"(x1), "+v"(x3));
          union { u32 uw[4]; bf16x8 vv; } U;
          U.uw[0] = x0; U.uw[1] = x1; U.uw[2] = x2; U.uw[3] = x3;
          pf[s][c2] = U.vv;
        }

      // ---- PV: O^T[64d][32q] += V^T * P^T ----
      __builtin_amdgcn_s_setprio(1);
      #pragma unroll
      for (int s = 0; s < 2; ++s)
        #pragma unroll
        for (int c2 = 0; c2 < 2; ++c2) {
          oacc[0] = __builtin_amdgcn_mfma_f32_32x32x16_bf16(vf[0][s][c2], pf[s][c2], oacc[0], 0, 0, 0);
          oacc[1] = __builtin_amdgcn_mfma_f32_32x32x16_bf16(vf[1][s][c2], pf[s][c2], oacc[1], 0, 0, 0);
        }
      __builtin_amdgcn_s_setprio(0);
    }
  }
  #undef STAGE

  // ---- split-K merge over u (R9-proven), scratch = kbuf reuse ----
  __syncthreads();                               // all waves done reading kbuf/vbuf
  float l_run = ((l_vec[0] + l_vec[1]) + (l_vec[2] + l_vec[3]))
              + ((l_vec[4] + l_vec[5]) + (l_vec[6] + l_vec[7]));
  float* ms = ((float*)kbuf) + (r * 64 + lane) * 37;   // 2 pairs x 64 lanes x 37 f32
  if (u_ == 1) {
    #pragma unroll
    for (int dt = 0; dt < 2; ++dt)
      #pragma unroll
      for (int e = 0; e < 16; ++e) ms[dt * 16 + e] = oacc[dt][e];
    ms[32] = m_run;
    ms[33] = l_run;
  }
  __syncthreads();
  if (u_ == 0) {
    const float m1 = ms[32], l1 = ms[33];
    const float mt = fmaxf(m_run, m1);
    const float s0 = __builtin_amdgcn_exp2f(m_run - mt);
    const float s1 = __builtin_amdgcn_exp2f(m1 - mt);    // m1=-1e30 (idle wave) -> 0
    float lt = l_run * s0 + l1 * s1;
    lt += __shfl_xor(lt, 32);                            // cross-half partial l
    const float inv = 1.f / (lt + 1e-8f);
    #pragma unroll
    for (int dt = 0; dt < 2; ++dt)
      #pragma unroll
      for (int n = 0; n < 4; ++n) {
        const float o0 = (oacc[dt][4 * n + 0] * s0 + ms[dt * 16 + 4 * n + 0] * s1) * inv;
        const float o1 = (oacc[dt][4 * n + 1] * s0 + ms[dt * 16 + 4 * n + 1] * s1) * inv;
        const float o2 = (oacc[dt][4 * n + 2] * s0 + ms[dt * 16 + 4 * n + 2] * s1) * inv;
        const float o3 = (oacc[dt][4 * n + 3] * s0 + ms[dt * 16 + 4 * n + 3] * s1) * inv;
        u32 lo  = cvt_pk_bf16(o0, o1);
        u32 hi2 = cvt_pk_bf16(o2, o3);
        // d = 32dt + 8n + 4hi + {0..3}
        *(uint2*)&Y[(size_t)(b_ * TT + qg) * CC + h * 64 + 32 * dt + 8 * n + 4 * hi]
          = make_uint2(lo, hi2);
      }
  }
}

// ---------------- kernel 3: output projection -> fp32 d_out -------------------------
// 128x64 tiles -> grid 512 = 2 blocks/CU (was 256 = 1/CU, zero cross-block TLP --
// the mechanism R14/R15 proved critical). LDS 12KB (A 8K + B 4K), acc[4][2].
__global__ __launch_bounds__(256)
void k_gemm_o(const u16* __restrict__ Yb, const u16* __restrict__ Wo,
              const float* __restrict__ so, const float* __restrict__ bo,
              float* __restrict__ out) {
  __shared__ u16 As[128 * 32];         // 8KB
  __shared__ u16 Bs[64 * 32];          // 4KB
  const int bid = blockIdx.x;
  const int brow = (bid & 31) * 128;
  const int bcol = (bid >> 5) * 64;    // 16 col tiles of 64
  const int tid  = threadIdx.x;
  const int w    = tid >> 6;
  const int lane = tid & 63;
  const int q = lane & 15, g = lane >> 4;
  const int wm = w >> 1, wn = w & 1;   // wave sub-tile: 64 rows x 32 cols

  f32x4 acc[4][2];
  #pragma unroll
  for (int a = 0; a < 4; ++a)
    #pragma unroll
    for (int b = 0; b < 2; ++b) { f32x4 z = {0.f, 0.f, 0.f, 0.f}; acc[a][b] = z; }

  for (int kt = 0; kt < CC / 32; ++kt) {
    // A: 512 granules (2 rounds of 256); B: 256 granules (1 round)
    #pragma unroll
    for (int i = 0; i < 2; ++i) {
      int Lg  = i * 256 + tid;
      int row = Lg >> 2, gc = Lg & 3;
      gload_lds16(Yb + (size_t)(brow + row) * CC + kt * 32 + gc * 8, As + (i * 256 + w * 64) * 8);
    }
    {
      int row = tid >> 2, gc = tid & 3;           // rows 0..63
      gload_lds16(Wo + (size_t)(bcol + row) * CC + kt * 32 + gc * 8, Bs + (w * 64) * 8);
    }
    __syncthreads();
    bf16x8 af[4], bff[2];
    #pragma unroll
    for (int a = 0; a < 4; ++a) af[a]  = *(const bf16x8*)&As[(wm * 64 + a * 16 + q) * 32 + g * 8];
    #pragma unroll
    for (int b = 0; b < 2; ++b) bff[b] = *(const bf16x8*)&Bs[(wn * 32 + b * 16 + q) * 32 + g * 8];
    #pragma unroll
    for (int a = 0; a < 4; ++a) {
      #pragma unroll
      for (int b = 0; b < 2; ++b) {
        acc[a][b] = __builtin_amdgcn_mfma_f32_16x16x32_bf16(af[a], bff[b], acc[a][b], 0, 0, 0);
      }
    }
    __syncthreads();
  }

  #pragma unroll
  for (int bt = 0; bt < 2; ++bt) {
    const int c = bcol + wn * 32 + bt * 16 + q;
    const float sc = so[c], bi = bo[c];
    #pragma unroll
    for (int a = 0; a < 4; ++a) {
      const int mbase = brow + wm * 64 + a * 16 + 4 * g;
      #pragma unroll
      for (int r = 0; r < 4; ++r) {
        out[(size_t)(mbase + r) * CC + c] = acc[a][bt][r] * sc + bi;
      }
    }
  }
}

// ---------------- launcher -----------------------------------------------------------
extern "C" void kernel_launch(void* const* d_in, const int* in_sizes, int n_in,
                              void* d_out, int out_size, void* d_ws, size_t ws_size,
                              hipStream_t stream) {
  const float* x  = (const float*)d_in[0];
  const int*   wq = (const int*)d_in[1];
  const float* sq = (const float*)d_in[2];
  const float* bq = (const float*)d_in[3];
  const int*   wk = (const int*)d_in[4];
  const float* sk = (const float*)d_in[5];
  const float* bk = (const float*)d_in[6];
  const int*   wv = (const int*)d_in[7];
  const float* sv = (const float*)d_in[8];
  const float* bv = (const float*)d_in[9];
  const int*   wo = (const int*)d_in[10];
  const float* so = (const float*)d_in[11];
  const float* bo = (const float*)d_in[12];

  const size_t NEED = (40u << 20);
  if (ws_size < NEED) {   // diagnostic: error magnitude ~9999 => scratch too small
    k_sentinel<<<dim3((out_size + 255) / 256), dim3(256), 0, stream>>>((float*)d_out, out_size);
    return;
  }

  char* ws = (char*)d_ws;
  u16* xb = (u16*)(ws);                      // 8 MB  (x bf16; reused as Y later)
  u16* wb = (u16*)(ws + (8u  << 20));        // 8 MB  (4 weight matrices bf16)
  u16* Qb = (u16*)(ws + (16u << 20));        // 8 MB
  u16* Kb = (u16*)(ws + (24u << 20));        // 8 MB
  u16* Vt = (u16*)(ws + (32u << 20));        // 8 MB  (V^T, written directly by QKV GEMM)
  u16* Yb = xb;                              // x dead after QKV GEMM

  k_convert <<<dim3(8192), dim3(256), 0, stream>>>(x, wq, wk, wv, wo, xb, wb);
  k_gemm_qkv<<<dim3(768),  dim3(256), 0, stream>>>(xb, wb, sq, bq, sk, bk, sv, bv, Qb, Kb, Vt);
  k_attn    <<<dim3(1024), dim3(256), 0, stream>>>(Qb, Kb, Vt, Yb);
  k_gemm_o  <<<dim3(512),  dim3(256), 0, stream>>>(Yb, wb + (3u << 20), so, bo, (float*)d_out);
}